// Round 3
// baseline (573.372 us; speedup 1.0000x reference)
//
#include <hip/hip_runtime.h>
#include <math.h>

// ---------------------------------------------------------------------------
// Multi-layer diffractive optical model (4 layers, 48 images of 512x512 c64).
//   field = x*exp(i*phase*coeff); 4x [prop(H1); phase]; prop(H1*Hf); |field|^2
// FFT: 512-pt radix-8 Stockham, 3 stages, 64 lanes/transform, 8 elems/lane.
// Row pass fuses rowIFFT -> phase -> rowFFT; col pass fuses colFFT -> xH -> colIFFT.
// Col pass v2: 16 cols / 1024-thread block -> 64B contiguous segments,
//   single 64KB LDS buffer (3 syncs/FFT), target 32 waves/CU.
// H transfer fns precomputed once into ws (H1 and fused H1*Hf).
// Field planes: Re = d_out (rewritten each call), Im = d_ws.
// ---------------------------------------------------------------------------

#define TWOPI_F 6.2831854820251465f
#define RSQ2    0.70710678f
#define NPIX    (48*512*512)

__device__ __forceinline__ float2 cadd(float2 a, float2 b){ return make_float2(a.x+b.x, a.y+b.y); }
__device__ __forceinline__ float2 csub(float2 a, float2 b){ return make_float2(a.x-b.x, a.y-b.y); }
__device__ __forceinline__ float2 cmul(float2 a, float2 b){ return make_float2(a.x*b.x - a.y*b.y, a.x*b.y + a.y*b.x); }

template<int S> __device__ __forceinline__ float2 mul_i(float2 a){   // * (S*i)
  return (S>0) ? make_float2(-a.y, a.x) : make_float2(a.y, -a.x);
}
template<int S> __device__ __forceinline__ float2 mul_w1(float2 a){  // * (1 + S*i)/sqrt2
  return (S>0) ? make_float2(RSQ2*(a.x-a.y), RSQ2*(a.x+a.y))
               : make_float2(RSQ2*(a.x+a.y), RSQ2*(a.y-a.x));
}
template<int S> __device__ __forceinline__ float2 mul_w3(float2 a){  // * (-1 + S*i)/sqrt2
  return (S>0) ? make_float2(RSQ2*(-a.x-a.y), RSQ2*(a.x-a.y))
               : make_float2(RSQ2*(a.y-a.x), RSQ2*(-a.x-a.y));
}
// tw stored with FORWARD sign (exp(-i theta)); S=+1 uses conjugate.
template<int S> __device__ __forceinline__ float2 cmul_tw(float2 v, float2 w){
  float wy = (S>0) ? -w.y : w.y;
  return make_float2(v.x*w.x - v.y*wy, v.x*wy + v.y*w.x);
}

// 8-point DIF DFT; outputs bit-reversed: A_k = d[km[k]], km = {0,4,2,6,1,5,3,7}
template<int S>
__device__ __forceinline__ void dft8(const float2* a, float2* d){
  float2 b0=cadd(a[0],a[4]), b1=cadd(a[1],a[5]), b2=cadd(a[2],a[6]), b3=cadd(a[3],a[7]);
  float2 b4=csub(a[0],a[4]);
  float2 b5=mul_w1<S>(csub(a[1],a[5]));
  float2 b6=mul_i<S> (csub(a[2],a[6]));
  float2 b7=mul_w3<S>(csub(a[3],a[7]));
  float2 c0=cadd(b0,b2), c2=csub(b0,b2);
  float2 c1=cadd(b1,b3), c3=mul_i<S>(csub(b1,b3));
  float2 c4=cadd(b4,b6), c6=csub(b4,b6);
  float2 c5=cadd(b5,b7), c7=mul_i<S>(csub(b5,b7));
  d[0]=cadd(c0,c1); d[1]=csub(c0,c1);
  d[2]=cadd(c2,c3); d[3]=csub(c2,c3);
  d[4]=cadd(c4,c5); d[5]=csub(c4,c5);
  d[6]=cadd(c6,c7); d[7]=csub(c6,c7);
}

__device__ __forceinline__ int SWZ(int i){ return i ^ ((i>>3)&7); }  // LDS anti-conflict swizzle (stride-8 layouts)

// Per-thread twiddles (forward sign), computed once per kernel.
__device__ __forceinline__ void make_tw(int t, float2* tw0, float2* tw1){
  float sn, cs;
  __sincosf((TWOPI_F/512.0f)*(float)t, &sn, &cs);
  float2 w0 = make_float2(cs, -sn);
  tw0[0] = make_float2(1.0f, 0.0f);
  #pragma unroll
  for(int k=1;k<8;k++) tw0[k] = cmul(tw0[k-1], w0);
  int p = t>>3;
  __sincosf((TWOPI_F/64.0f)*(float)p, &sn, &cs);
  float2 w1 = make_float2(cs, -sn);
  tw1[0] = make_float2(1.0f, 0.0f);
  #pragma unroll
  for(int k=1;k<8;k++) tw1[k] = cmul(tw1[k-1], w1);
}

// 512-pt FFT, two-buffer ping-pong (row kernels). Input a[r]=elem(t+64r); o[k]=X[t+64k]*scale.
template<int S, int STRIDE>
__device__ __forceinline__ void fft512(float2* a, float2* o, float2* B0, float2* B1, int t,
                                       float scale, const float2* tw0, const float2* tw1){
  const int km[8] = {0,4,2,6,1,5,3,7};
  float2 d[8];
  dft8<S>(a, d);                                    // stage 0: n=512, s=1, p=t
  #pragma unroll
  for(int k=0;k<8;k++)
    B0[SWZ(8*t+k)*STRIDE] = (k==0) ? d[km[0]] : cmul_tw<S>(d[km[k]], tw0[k]);
  __syncthreads();
  #pragma unroll
  for(int r=0;r<8;r++) a[r] = B0[SWZ(t+64*r)*STRIDE];
  dft8<S>(a, d);                                    // stage 1: n=64, s=8
  {
    int p = t>>3, q = t&7;
    #pragma unroll
    for(int k=0;k<8;k++)
      B1[SWZ(q + 64*p + 8*k)*STRIDE] = (k==0) ? d[km[0]] : cmul_tw<S>(d[km[k]], tw1[k]);
  }
  __syncthreads();
  #pragma unroll
  for(int r=0;r<8;r++) a[r] = B1[SWZ(t+64*r)*STRIDE];
  dft8<S>(a, d);                                    // stage 2: n=8, s=64, no twiddle
  #pragma unroll
  for(int k=0;k<8;k++) o[k] = make_float2(d[km[k]].x*scale, d[km[k]].y*scale);
}

// 512-pt FFT, single shared buffer, stride 16 (col kernel). Caller must sync
// before the next write into B after this returns (last op is a read).
template<int S>
__device__ __forceinline__ void fft512_1b(float2* a, float2* o, float2* B, int t,
                                          float scale, const float2* tw0, const float2* tw1){
  const int km[8] = {0,4,2,6,1,5,3,7};
  float2 d[8];
  dft8<S>(a, d);                                    // stage 0
  #pragma unroll
  for(int k=0;k<8;k++)
    B[(8*t+k)*16] = (k==0) ? d[km[0]] : cmul_tw<S>(d[km[k]], tw0[k]);
  __syncthreads();
  #pragma unroll
  for(int r=0;r<8;r++) a[r] = B[(t+64*r)*16];
  __syncthreads();
  dft8<S>(a, d);                                    // stage 1
  {
    int p = t>>3, q = t&7;
    #pragma unroll
    for(int k=0;k<8;k++)
      B[(q + 64*p + 8*k)*16] = (k==0) ? d[km[0]] : cmul_tw<S>(d[km[k]], tw1[k]);
  }
  __syncthreads();
  #pragma unroll
  for(int r=0;r<8;r++) a[r] = B[(t+64*r)*16];
  dft8<S>(a, d);                                    // stage 2, regs only
  #pragma unroll
  for(int k=0;k<8;k++) o[k] = make_float2(d[km[k]].x*scale, d[km[k]].y*scale);
}

// --- H transfer-function tables: H1(z=0.03) and H12 = H(0.03)*H(0.05) --------

__device__ __forceinline__ float2 phase_of(float kz, float zf){
  float tt = __fmul_rn(kz, zf);
  double dt = (double)tt;                          // accurate mod-2pi reduction
  double q  = rint(dt * 0.15915494309189535);
  double rr = fma(-q, 6.283185307179586, dt);
  float sn, cs; __sincosf((float)rr, &sn, &cs);
  return make_float2(cs, sn);
}

__global__ __launch_bounds__(256) void k_htab(const float* __restrict__ lams,
                                              float2* __restrict__ H1, float2* __restrict__ H12){
  int e = blockIdx.x*256 + threadIdx.x;            // e < 3*512*512
  int c = e >> 18, fy = (e>>9)&511, col = e&511;
  const float lam = lams[c];
  const float il  = 1.0f / lam;
  const float il2 = __fmul_rn(il, il);
  const float DEN = (float)(512.0 * 8e-6);
  int   sx  = (col < 256) ? col : col - 512;
  int   sy  = (fy  < 256) ? fy  : fy  - 512;
  float fxv = (float)sx / DEN, fyv = (float)sy / DEN;
  float arg = __fsub_rn(il2, __fadd_rn(__fmul_rn(fxv,fxv), __fmul_rn(fyv,fyv)));
  float2 h1 = make_float2(0.0f,0.0f), h12 = h1;
  if(arg > 0.0f){
    float s  = (float)sqrt((double)arg);           // correctly-rounded f32 sqrt
    float kz = __fmul_rn(6.2831854820251465f, s);
    h1  = phase_of(kz, 0.03f);
    h12 = cmul(h1, phase_of(kz, 0.05f));
  }
  H1[e] = h1; H12[e] = h12;
}

// --- Row pass kernels: one wave per row, 4 rows per block ---------------------

__global__ __launch_bounds__(256) void k_row_first(
    const float* __restrict__ x, float* __restrict__ re, float* __restrict__ im,
    const float* __restrict__ phases, const float* __restrict__ coeffs)
{
  __shared__ float2 lds[4][2][512];
  const int w = threadIdx.x >> 6, t = threadIdx.x & 63;
  const int img = blockIdx.x, c = img % 3;
  const int row = (blockIdx.y<<2) + w;
  const int base = (img*512 + row)*512;
  const float* ph = phases + row*512;              // layer 0
  const float coeff = coeffs[c];
  float2 tw0[8], tw1[8]; make_tw(t, tw0, tw1);
  float2 a[8], o[8];
  #pragma unroll
  for(int r=0;r<8;r++){
    int i = t + (r<<6);
    float xv = x[base+i];
    float th = __fmul_rn(ph[i], coeff);
    float sn, cs; __sincosf(th, &sn, &cs);
    a[r] = make_float2(xv*cs, xv*sn);
  }
  fft512<-1,1>(a, o, lds[w][0], lds[w][1], t, 1.0f, tw0, tw1);
  #pragma unroll
  for(int k=0;k<8;k++){ int i=t+(k<<6); re[base+i]=o[k].x; im[base+i]=o[k].y; }
}

__global__ __launch_bounds__(256) void k_row_mid(
    float* __restrict__ re, float* __restrict__ im,
    const float* __restrict__ phases, const float* __restrict__ coeffs, int layer)
{
  __shared__ float2 lds[4][2][512];
  const int w = threadIdx.x >> 6, t = threadIdx.x & 63;
  const int img = blockIdx.x, c = img % 3;
  const int row = (blockIdx.y<<2) + w;
  const int base = (img*512 + row)*512;
  const float* ph = phases + (layer*512 + row)*512;
  const float coeff = coeffs[layer*3 + c];
  float2 tw0[8], tw1[8]; make_tw(t, tw0, tw1);
  float2 a[8], o[8];
  #pragma unroll
  for(int r=0;r<8;r++){ int i=t+(r<<6); a[r]=make_float2(re[base+i], im[base+i]); }
  fft512<+1,1>(a, o, lds[w][0], lds[w][1], t, 1.0f/512.0f, tw0, tw1);   // row IFFT
  #pragma unroll
  for(int k=0;k<8;k++){
    int i = t + (k<<6);
    float th = __fmul_rn(ph[i], coeff);
    float sn, cs; __sincosf(th, &sn, &cs);
    a[k] = cmul(o[k], make_float2(cs, sn));
  }
  fft512<-1,1>(a, o, lds[w][0], lds[w][1], t, 1.0f, tw0, tw1);          // row FFT
  #pragma unroll
  for(int k=0;k<8;k++){ int i=t+(k<<6); re[base+i]=o[k].x; im[base+i]=o[k].y; }
}

__global__ __launch_bounds__(256) void k_row_last(
    const float* __restrict__ re, const float* __restrict__ im, float* __restrict__ out)
{
  __shared__ float2 lds[4][2][512];
  const int w = threadIdx.x >> 6, t = threadIdx.x & 63;
  const int img = blockIdx.x;
  const int row = (blockIdx.y<<2) + w;
  const int base = (img*512 + row)*512;
  float2 tw0[8], tw1[8]; make_tw(t, tw0, tw1);
  float2 a[8], o[8];
  #pragma unroll
  for(int r=0;r<8;r++){ int i=t+(r<<6); a[r]=make_float2(re[base+i], im[base+i]); }
  fft512<+1,1>(a, o, lds[w][0], lds[w][1], t, 1.0f/512.0f, tw0, tw1);   // row IFFT
  #pragma unroll
  for(int k=0;k<8;k++){ int i=t+(k<<6); out[base+i] = o[k].x*o[k].x + o[k].y*o[k].y; }
}

// --- Column pass v2: colFFT -> xH -> colIFFT; 16 cols / 1024-thread block -----
// 64B contiguous global segments; single 64KB LDS buffer; aim 2 blocks/CU.

template<bool TAB>
__global__ __launch_bounds__(1024, 8) void k_col16(
    float* __restrict__ re, float* __restrict__ im,
    const float2* __restrict__ Htab, const float* __restrict__ lams, float z1, float z2)
{
  __shared__ float2 lds[512][16];       // 64 KiB; bank spread uniform at stride 16
  const int cx = threadIdx.x & 15, t = threadIdx.x >> 4;
  const int img = blockIdx.x, c = img % 3;
  const int col = (blockIdx.y<<4) + cx;
  const int ibase = (img<<18) + col;
  float2 tw0[8], tw1[8]; make_tw(t, tw0, tw1);
  float2 a[8], o[8];
  #pragma unroll
  for(int r=0;r<8;r++){ int gi = ibase + ((t+(r<<6))<<9); a[r]=make_float2(re[gi], im[gi]); }
  fft512_1b<-1>(a, o, &lds[0][cx], t, 1.0f, tw0, tw1);          // col FFT

  if(TAB){
    #pragma unroll
    for(int k=0;k<8;k++){
      int fy = t + (k<<6);
      float2 h = Htab[(c<<18) + (fy<<9) + col];
      a[k] = cmul(o[k], h);
    }
  } else {
    const float lam = lams[c];
    const float il  = 1.0f / lam;
    const float il2 = __fmul_rn(il, il);
    const float DEN = (float)(512.0 * 8e-6);
    int   sx  = (col < 256) ? col : col - 512;
    float fxv = (float)sx / DEN;
    float fx2 = __fmul_rn(fxv, fxv);
    #pragma unroll
    for(int k=0;k<8;k++){
      int fy = t + (k<<6);
      int sy = (fy < 256) ? fy : fy - 512;
      float fyv = (float)sy / DEN;
      float arg = __fsub_rn(il2, __fadd_rn(fx2, __fmul_rn(fyv,fyv)));
      float2 h = make_float2(0.0f, 0.0f);
      if(arg > 0.0f){
        float s  = (float)sqrt((double)arg);
        float kz = __fmul_rn(6.2831854820251465f, s);
        h = phase_of(kz, z1);
        if(z2 != 0.0f) h = cmul(h, phase_of(kz, z2));
      }
      a[k] = cmul(o[k], h);
    }
  }
  __syncthreads();                                               // LDS reuse fence
  fft512_1b<+1>(a, o, &lds[0][cx], t, 1.0f/512.0f, tw0, tw1);   // col IFFT
  #pragma unroll
  for(int k=0;k<8;k++){ int gi = ibase + ((t+(k<<6))<<9); re[gi]=o[k].x; im[gi]=o[k].y; }
}

// ---------------------------------------------------------------------------

extern "C" void kernel_launch(void* const* d_in, const int* in_sizes, int n_in,
                              void* d_out, int out_size, void* d_ws, size_t ws_size,
                              hipStream_t stream)
{
  const float* x      = (const float*)d_in[0];
  const float* phases = (const float*)d_in[1];
  const float* coeffs = (const float*)d_in[2];
  const float* lams   = (const float*)d_in[3];
  float* out = (float*)d_out;

  float* re = out;                       // Re plane reuses output buffer
  float* im = (float*)d_ws;              // Im plane: 48*512*512*4 = 50331648 B
  const size_t imB = (size_t)NPIX*4;
  const size_t tabB = (size_t)3*512*512*8;
  const bool tab = ws_size >= imB + 2*tabB;
  float2* H1  = (float2*)((char*)d_ws + imB);
  float2* H12 = H1 + 3*512*512;

  dim3 gA(48,128), bA(256);
  dim3 gB(48,32),  bB(1024);

  if(tab) k_htab<<<dim3(3*512*512/256), dim3(256), 0, stream>>>(lams, H1, H12);

  k_row_first<<<gA, bA, 0, stream>>>(x, re, im, phases, coeffs);          // phase0 + rowFFT
  for(int l=1; l<=3; l++){
    if(tab) k_col16<true ><<<gB, bB, 0, stream>>>(re, im, H1, lams, 0.03f, 0.0f);
    else    k_col16<false><<<gB, bB, 0, stream>>>(re, im, nullptr, lams, 0.03f, 0.0f);
    k_row_mid<<<gA, bA, 0, stream>>>(re, im, phases, coeffs, l);          // rowIFFT+phase+rowFFT
  }
  // fused final double-propagation: H(0.03)*H(0.05)
  if(tab) k_col16<true ><<<gB, bB, 0, stream>>>(re, im, H12, lams, 0.03f, 0.0f);
  else    k_col16<false><<<gB, bB, 0, stream>>>(re, im, nullptr, lams, 0.03f, 0.05f);
  k_row_last<<<gA, bA, 0, stream>>>(re, im, out);                         // rowIFFT + |.|^2
}

// Round 4
// 379.272 us; speedup vs baseline: 1.5118x; 1.5118x over previous
//
#include <hip/hip_runtime.h>
#include <math.h>

// ---------------------------------------------------------------------------
// Multi-layer diffractive optical model (4 layers, 48 images of 512x512 c64).
//   field = x*exp(i*phase*coeff); 4x [prop(H1); phase]; prop(H1*Hf); |field|^2
// FFT: 512-pt radix-8 Stockham, 3 stages, 64 lanes/transform, 8 elems/lane.
// Row pass fuses rowIFFT -> phase -> rowFFT; col pass fuses colFFT -> xH -> colIFFT.
// Col pass: 16 cols / 1024-thread block -> 64B contiguous segments, single
//   64KB LDS buffer. launch_bounds(1024,4): VGPR cap 128 -- (1024,8) forced
//   a 32-VGPR allocation that spilled FFT state to scratch (+300MB/dispatch).
// H transfer fns precomputed once into ws (H1 and fused H1*Hf).
// Field planes: Re = d_out (rewritten each call), Im = d_ws.
// ---------------------------------------------------------------------------

#define TWOPI_F 6.2831854820251465f
#define RSQ2    0.70710678f
#define NPIX    (48*512*512)

__device__ __forceinline__ float2 cadd(float2 a, float2 b){ return make_float2(a.x+b.x, a.y+b.y); }
__device__ __forceinline__ float2 csub(float2 a, float2 b){ return make_float2(a.x-b.x, a.y-b.y); }
__device__ __forceinline__ float2 cmul(float2 a, float2 b){ return make_float2(a.x*b.x - a.y*b.y, a.x*b.y + a.y*b.x); }

template<int S> __device__ __forceinline__ float2 mul_i(float2 a){   // * (S*i)
  return (S>0) ? make_float2(-a.y, a.x) : make_float2(a.y, -a.x);
}
template<int S> __device__ __forceinline__ float2 mul_w1(float2 a){  // * (1 + S*i)/sqrt2
  return (S>0) ? make_float2(RSQ2*(a.x-a.y), RSQ2*(a.x+a.y))
               : make_float2(RSQ2*(a.x+a.y), RSQ2*(a.y-a.x));
}
template<int S> __device__ __forceinline__ float2 mul_w3(float2 a){  // * (-1 + S*i)/sqrt2
  return (S>0) ? make_float2(RSQ2*(-a.x-a.y), RSQ2*(a.x-a.y))
               : make_float2(RSQ2*(a.y-a.x), RSQ2*(-a.x-a.y));
}
// tw stored with FORWARD sign (exp(-i theta)); S=+1 uses conjugate.
template<int S> __device__ __forceinline__ float2 cmul_tw(float2 v, float2 w){
  float wy = (S>0) ? -w.y : w.y;
  return make_float2(v.x*w.x - v.y*wy, v.x*wy + v.y*w.x);
}

// 8-point DIF DFT; outputs bit-reversed: A_k = d[km[k]], km = {0,4,2,6,1,5,3,7}
template<int S>
__device__ __forceinline__ void dft8(const float2* a, float2* d){
  float2 b0=cadd(a[0],a[4]), b1=cadd(a[1],a[5]), b2=cadd(a[2],a[6]), b3=cadd(a[3],a[7]);
  float2 b4=csub(a[0],a[4]);
  float2 b5=mul_w1<S>(csub(a[1],a[5]));
  float2 b6=mul_i<S> (csub(a[2],a[6]));
  float2 b7=mul_w3<S>(csub(a[3],a[7]));
  float2 c0=cadd(b0,b2), c2=csub(b0,b2);
  float2 c1=cadd(b1,b3), c3=mul_i<S>(csub(b1,b3));
  float2 c4=cadd(b4,b6), c6=csub(b4,b6);
  float2 c5=cadd(b5,b7), c7=mul_i<S>(csub(b5,b7));
  d[0]=cadd(c0,c1); d[1]=csub(c0,c1);
  d[2]=cadd(c2,c3); d[3]=csub(c2,c3);
  d[4]=cadd(c4,c5); d[5]=csub(c4,c5);
  d[6]=cadd(c6,c7); d[7]=csub(c6,c7);
}

__device__ __forceinline__ int SWZ(int i){ return i ^ ((i>>3)&7); }  // LDS anti-conflict swizzle (stride-8 layouts)

// Per-thread twiddles (forward sign), computed once per kernel.
__device__ __forceinline__ void make_tw(int t, float2* tw0, float2* tw1){
  float sn, cs;
  __sincosf((TWOPI_F/512.0f)*(float)t, &sn, &cs);
  float2 w0 = make_float2(cs, -sn);
  tw0[0] = make_float2(1.0f, 0.0f);
  #pragma unroll
  for(int k=1;k<8;k++) tw0[k] = cmul(tw0[k-1], w0);
  int p = t>>3;
  __sincosf((TWOPI_F/64.0f)*(float)p, &sn, &cs);
  float2 w1 = make_float2(cs, -sn);
  tw1[0] = make_float2(1.0f, 0.0f);
  #pragma unroll
  for(int k=1;k<8;k++) tw1[k] = cmul(tw1[k-1], w1);
}

// 512-pt FFT, two-buffer ping-pong (row kernels). Input a[r]=elem(t+64r); o[k]=X[t+64k]*scale.
template<int S, int STRIDE>
__device__ __forceinline__ void fft512(float2* a, float2* o, float2* B0, float2* B1, int t,
                                       float scale, const float2* tw0, const float2* tw1){
  const int km[8] = {0,4,2,6,1,5,3,7};
  float2 d[8];
  dft8<S>(a, d);                                    // stage 0: n=512, s=1, p=t
  #pragma unroll
  for(int k=0;k<8;k++)
    B0[SWZ(8*t+k)*STRIDE] = (k==0) ? d[km[0]] : cmul_tw<S>(d[km[k]], tw0[k]);
  __syncthreads();
  #pragma unroll
  for(int r=0;r<8;r++) a[r] = B0[SWZ(t+64*r)*STRIDE];
  dft8<S>(a, d);                                    // stage 1: n=64, s=8
  {
    int p = t>>3, q = t&7;
    #pragma unroll
    for(int k=0;k<8;k++)
      B1[SWZ(q + 64*p + 8*k)*STRIDE] = (k==0) ? d[km[0]] : cmul_tw<S>(d[km[k]], tw1[k]);
  }
  __syncthreads();
  #pragma unroll
  for(int r=0;r<8;r++) a[r] = B1[SWZ(t+64*r)*STRIDE];
  dft8<S>(a, d);                                    // stage 2: n=8, s=64, no twiddle
  #pragma unroll
  for(int k=0;k<8;k++) o[k] = make_float2(d[km[k]].x*scale, d[km[k]].y*scale);
}

// 512-pt FFT, single shared buffer, stride 16 (col kernel). Caller must sync
// before the next write into B after this returns (last op is a read).
template<int S>
__device__ __forceinline__ void fft512_1b(float2* a, float2* o, float2* B, int t,
                                          float scale, const float2* tw0, const float2* tw1){
  const int km[8] = {0,4,2,6,1,5,3,7};
  float2 d[8];
  dft8<S>(a, d);                                    // stage 0
  #pragma unroll
  for(int k=0;k<8;k++)
    B[(8*t+k)*16] = (k==0) ? d[km[0]] : cmul_tw<S>(d[km[k]], tw0[k]);
  __syncthreads();
  #pragma unroll
  for(int r=0;r<8;r++) a[r] = B[(t+64*r)*16];
  __syncthreads();
  dft8<S>(a, d);                                    // stage 1
  {
    int p = t>>3, q = t&7;
    #pragma unroll
    for(int k=0;k<8;k++)
      B[(q + 64*p + 8*k)*16] = (k==0) ? d[km[0]] : cmul_tw<S>(d[km[k]], tw1[k]);
  }
  __syncthreads();
  #pragma unroll
  for(int r=0;r<8;r++) a[r] = B[(t+64*r)*16];
  dft8<S>(a, d);                                    // stage 2, regs only
  #pragma unroll
  for(int k=0;k<8;k++) o[k] = make_float2(d[km[k]].x*scale, d[km[k]].y*scale);
}

// --- H transfer-function tables: H1(z=0.03) and H12 = H(0.03)*H(0.05) --------

__device__ __forceinline__ float2 phase_of(float kz, float zf){
  float tt = __fmul_rn(kz, zf);
  double dt = (double)tt;                          // accurate mod-2pi reduction
  double q  = rint(dt * 0.15915494309189535);
  double rr = fma(-q, 6.283185307179586, dt);
  float sn, cs; __sincosf((float)rr, &sn, &cs);
  return make_float2(cs, sn);
}

__global__ __launch_bounds__(256) void k_htab(const float* __restrict__ lams,
                                              float2* __restrict__ H1, float2* __restrict__ H12){
  int e = blockIdx.x*256 + threadIdx.x;            // e < 3*512*512
  int c = e >> 18, fy = (e>>9)&511, col = e&511;
  const float lam = lams[c];
  const float il  = 1.0f / lam;
  const float il2 = __fmul_rn(il, il);
  const float DEN = (float)(512.0 * 8e-6);
  int   sx  = (col < 256) ? col : col - 512;
  int   sy  = (fy  < 256) ? fy  : fy  - 512;
  float fxv = (float)sx / DEN, fyv = (float)sy / DEN;
  float arg = __fsub_rn(il2, __fadd_rn(__fmul_rn(fxv,fxv), __fmul_rn(fyv,fyv)));
  float2 h1 = make_float2(0.0f,0.0f), h12 = h1;
  if(arg > 0.0f){
    float s  = (float)sqrt((double)arg);           // correctly-rounded f32 sqrt
    float kz = __fmul_rn(6.2831854820251465f, s);
    h1  = phase_of(kz, 0.03f);
    h12 = cmul(h1, phase_of(kz, 0.05f));
  }
  H1[e] = h1; H12[e] = h12;
}

// --- Row pass kernels: one wave per row, 4 rows per block ---------------------

__global__ __launch_bounds__(256) void k_row_first(
    const float* __restrict__ x, float* __restrict__ re, float* __restrict__ im,
    const float* __restrict__ phases, const float* __restrict__ coeffs)
{
  __shared__ float2 lds[4][2][512];
  const int w = threadIdx.x >> 6, t = threadIdx.x & 63;
  const int img = blockIdx.x, c = img % 3;
  const int row = (blockIdx.y<<2) + w;
  const int base = (img*512 + row)*512;
  const float* ph = phases + row*512;              // layer 0
  const float coeff = coeffs[c];
  float2 tw0[8], tw1[8]; make_tw(t, tw0, tw1);
  float2 a[8], o[8];
  #pragma unroll
  for(int r=0;r<8;r++){
    int i = t + (r<<6);
    float xv = x[base+i];
    float th = __fmul_rn(ph[i], coeff);
    float sn, cs; __sincosf(th, &sn, &cs);
    a[r] = make_float2(xv*cs, xv*sn);
  }
  fft512<-1,1>(a, o, lds[w][0], lds[w][1], t, 1.0f, tw0, tw1);
  #pragma unroll
  for(int k=0;k<8;k++){ int i=t+(k<<6); re[base+i]=o[k].x; im[base+i]=o[k].y; }
}

__global__ __launch_bounds__(256) void k_row_mid(
    float* __restrict__ re, float* __restrict__ im,
    const float* __restrict__ phases, const float* __restrict__ coeffs, int layer)
{
  __shared__ float2 lds[4][2][512];
  const int w = threadIdx.x >> 6, t = threadIdx.x & 63;
  const int img = blockIdx.x, c = img % 3;
  const int row = (blockIdx.y<<2) + w;
  const int base = (img*512 + row)*512;
  const float* ph = phases + (layer*512 + row)*512;
  const float coeff = coeffs[layer*3 + c];
  float2 tw0[8], tw1[8]; make_tw(t, tw0, tw1);
  float2 a[8], o[8];
  #pragma unroll
  for(int r=0;r<8;r++){ int i=t+(r<<6); a[r]=make_float2(re[base+i], im[base+i]); }
  fft512<+1,1>(a, o, lds[w][0], lds[w][1], t, 1.0f/512.0f, tw0, tw1);   // row IFFT
  #pragma unroll
  for(int k=0;k<8;k++){
    int i = t + (k<<6);
    float th = __fmul_rn(ph[i], coeff);
    float sn, cs; __sincosf(th, &sn, &cs);
    a[k] = cmul(o[k], make_float2(cs, sn));
  }
  fft512<-1,1>(a, o, lds[w][0], lds[w][1], t, 1.0f, tw0, tw1);          // row FFT
  #pragma unroll
  for(int k=0;k<8;k++){ int i=t+(k<<6); re[base+i]=o[k].x; im[base+i]=o[k].y; }
}

__global__ __launch_bounds__(256) void k_row_last(
    const float* __restrict__ re, const float* __restrict__ im, float* __restrict__ out)
{
  __shared__ float2 lds[4][2][512];
  const int w = threadIdx.x >> 6, t = threadIdx.x & 63;
  const int img = blockIdx.x;
  const int row = (blockIdx.y<<2) + w;
  const int base = (img*512 + row)*512;
  float2 tw0[8], tw1[8]; make_tw(t, tw0, tw1);
  float2 a[8], o[8];
  #pragma unroll
  for(int r=0;r<8;r++){ int i=t+(r<<6); a[r]=make_float2(re[base+i], im[base+i]); }
  fft512<+1,1>(a, o, lds[w][0], lds[w][1], t, 1.0f/512.0f, tw0, tw1);   // row IFFT
  #pragma unroll
  for(int k=0;k<8;k++){ int i=t+(k<<6); out[base+i] = o[k].x*o[k].x + o[k].y*o[k].y; }
}

// --- Column pass: colFFT -> xH -> colIFFT; 16 cols / 1024-thread block --------
// 64B contiguous global segments; single 64KB LDS buffer; VGPR cap 128.

template<bool TAB>
__global__ __launch_bounds__(1024, 4) void k_col16(
    float* __restrict__ re, float* __restrict__ im,
    const float2* __restrict__ Htab, const float* __restrict__ lams, float z1, float z2)
{
  __shared__ float2 lds[512][16];       // 64 KiB; bank spread uniform at stride 16
  const int cx = threadIdx.x & 15, t = threadIdx.x >> 4;
  const int img = blockIdx.x, c = img % 3;
  const int col = (blockIdx.y<<4) + cx;
  const int ibase = (img<<18) + col;
  float2 tw0[8], tw1[8]; make_tw(t, tw0, tw1);
  float2 a[8], o[8];
  #pragma unroll
  for(int r=0;r<8;r++){ int gi = ibase + ((t+(r<<6))<<9); a[r]=make_float2(re[gi], im[gi]); }
  fft512_1b<-1>(a, o, &lds[0][cx], t, 1.0f, tw0, tw1);          // col FFT

  if(TAB){
    #pragma unroll
    for(int k=0;k<8;k++){
      int fy = t + (k<<6);
      float2 h = Htab[(c<<18) + (fy<<9) + col];
      a[k] = cmul(o[k], h);
    }
  } else {
    const float lam = lams[c];
    const float il  = 1.0f / lam;
    const float il2 = __fmul_rn(il, il);
    const float DEN = (float)(512.0 * 8e-6);
    int   sx  = (col < 256) ? col : col - 512;
    float fxv = (float)sx / DEN;
    float fx2 = __fmul_rn(fxv, fxv);
    #pragma unroll
    for(int k=0;k<8;k++){
      int fy = t + (k<<6);
      int sy = (fy < 256) ? fy : fy - 512;
      float fyv = (float)sy / DEN;
      float arg = __fsub_rn(il2, __fadd_rn(fx2, __fmul_rn(fyv,fyv)));
      float2 h = make_float2(0.0f, 0.0f);
      if(arg > 0.0f){
        float s  = (float)sqrt((double)arg);
        float kz = __fmul_rn(6.2831854820251465f, s);
        h = phase_of(kz, z1);
        if(z2 != 0.0f) h = cmul(h, phase_of(kz, z2));
      }
      a[k] = cmul(o[k], h);
    }
  }
  __syncthreads();                                               // LDS reuse fence
  fft512_1b<+1>(a, o, &lds[0][cx], t, 1.0f/512.0f, tw0, tw1);   // col IFFT
  #pragma unroll
  for(int k=0;k<8;k++){ int gi = ibase + ((t+(k<<6))<<9); re[gi]=o[k].x; im[gi]=o[k].y; }
}

// ---------------------------------------------------------------------------

extern "C" void kernel_launch(void* const* d_in, const int* in_sizes, int n_in,
                              void* d_out, int out_size, void* d_ws, size_t ws_size,
                              hipStream_t stream)
{
  const float* x      = (const float*)d_in[0];
  const float* phases = (const float*)d_in[1];
  const float* coeffs = (const float*)d_in[2];
  const float* lams   = (const float*)d_in[3];
  float* out = (float*)d_out;

  float* re = out;                       // Re plane reuses output buffer
  float* im = (float*)d_ws;              // Im plane: 48*512*512*4 = 50331648 B
  const size_t imB = (size_t)NPIX*4;
  const size_t tabB = (size_t)3*512*512*8;
  const bool tab = ws_size >= imB + 2*tabB;
  float2* H1  = (float2*)((char*)d_ws + imB);
  float2* H12 = H1 + 3*512*512;

  dim3 gA(48,128), bA(256);
  dim3 gB(48,32),  bB(1024);

  if(tab) k_htab<<<dim3(3*512*512/256), dim3(256), 0, stream>>>(lams, H1, H12);

  k_row_first<<<gA, bA, 0, stream>>>(x, re, im, phases, coeffs);          // phase0 + rowFFT
  for(int l=1; l<=3; l++){
    if(tab) k_col16<true ><<<gB, bB, 0, stream>>>(re, im, H1, lams, 0.03f, 0.0f);
    else    k_col16<false><<<gB, bB, 0, stream>>>(re, im, nullptr, lams, 0.03f, 0.0f);
    k_row_mid<<<gA, bA, 0, stream>>>(re, im, phases, coeffs, l);          // rowIFFT+phase+rowFFT
  }
  // fused final double-propagation: H(0.03)*H(0.05)
  if(tab) k_col16<true ><<<gB, bB, 0, stream>>>(re, im, H12, lams, 0.03f, 0.0f);
  else    k_col16<false><<<gB, bB, 0, stream>>>(re, im, nullptr, lams, 0.03f, 0.05f);
  k_row_last<<<gA, bA, 0, stream>>>(re, im, out);                         // rowIFFT + |.|^2
}

// Round 5
// 369.177 us; speedup vs baseline: 1.5531x; 1.0273x over previous
//
#include <hip/hip_runtime.h>
#include <math.h>

// ---------------------------------------------------------------------------
// Multi-layer diffractive optical model (4 layers, 48 images of 512x512 c64).
//   field = x*exp(i*phase*coeff); 4x [prop(H1); phase]; prop(H1*Hf); |field|^2
// FFT: 512-pt radix-8 Stockham, 3 stages, 64 lanes/transform, 8 elems/lane.
// Row pass fuses rowIFFT -> phase -> rowFFT; col pass fuses colFFT -> xH -> colIFFT.
// Field layout (mode A, ws >= 113MB): interleaved float2 in d_ws -> 8B/lane
//   accesses, 128B col-pass segments, half the VMEM instructions.
//   Fallback mode B/C: split planes re=d_out, im=d_ws (round-4 behavior).
// H transfer fns precomputed once into ws (H1 and fused H1*Hf) when room.
// launch_bounds(1024,4) on col: VGPR cap 128 ((1024,8) forced spills).
// ---------------------------------------------------------------------------

#define TWOPI_F 6.2831854820251465f
#define RSQ2    0.70710678f
#define NPIX    (48*512*512)

__device__ __forceinline__ float2 cadd(float2 a, float2 b){ return make_float2(a.x+b.x, a.y+b.y); }
__device__ __forceinline__ float2 csub(float2 a, float2 b){ return make_float2(a.x-b.x, a.y-b.y); }
__device__ __forceinline__ float2 cmul(float2 a, float2 b){ return make_float2(a.x*b.x - a.y*b.y, a.x*b.y + a.y*b.x); }

template<int S> __device__ __forceinline__ float2 mul_i(float2 a){   // * (S*i)
  return (S>0) ? make_float2(-a.y, a.x) : make_float2(a.y, -a.x);
}
template<int S> __device__ __forceinline__ float2 mul_w1(float2 a){  // * (1 + S*i)/sqrt2
  return (S>0) ? make_float2(RSQ2*(a.x-a.y), RSQ2*(a.x+a.y))
               : make_float2(RSQ2*(a.x+a.y), RSQ2*(a.y-a.x));
}
template<int S> __device__ __forceinline__ float2 mul_w3(float2 a){  // * (-1 + S*i)/sqrt2
  return (S>0) ? make_float2(RSQ2*(-a.x-a.y), RSQ2*(a.x-a.y))
               : make_float2(RSQ2*(a.y-a.x), RSQ2*(-a.x-a.y));
}
// tw stored with FORWARD sign (exp(-i theta)); S=+1 uses conjugate.
template<int S> __device__ __forceinline__ float2 cmul_tw(float2 v, float2 w){
  float wy = (S>0) ? -w.y : w.y;
  return make_float2(v.x*w.x - v.y*wy, v.x*wy + v.y*w.x);
}

// 8-point DIF DFT; outputs bit-reversed: A_k = d[km[k]], km = {0,4,2,6,1,5,3,7}
template<int S>
__device__ __forceinline__ void dft8(const float2* a, float2* d){
  float2 b0=cadd(a[0],a[4]), b1=cadd(a[1],a[5]), b2=cadd(a[2],a[6]), b3=cadd(a[3],a[7]);
  float2 b4=csub(a[0],a[4]);
  float2 b5=mul_w1<S>(csub(a[1],a[5]));
  float2 b6=mul_i<S> (csub(a[2],a[6]));
  float2 b7=mul_w3<S>(csub(a[3],a[7]));
  float2 c0=cadd(b0,b2), c2=csub(b0,b2);
  float2 c1=cadd(b1,b3), c3=mul_i<S>(csub(b1,b3));
  float2 c4=cadd(b4,b6), c6=csub(b4,b6);
  float2 c5=cadd(b5,b7), c7=mul_i<S>(csub(b5,b7));
  d[0]=cadd(c0,c1); d[1]=csub(c0,c1);
  d[2]=cadd(c2,c3); d[3]=csub(c2,c3);
  d[4]=cadd(c4,c5); d[5]=csub(c4,c5);
  d[6]=cadd(c6,c7); d[7]=csub(c6,c7);
}

__device__ __forceinline__ int SWZ(int i){ return i ^ ((i>>3)&7); }  // LDS anti-conflict swizzle (stride-8 layouts)

// Per-thread twiddles (forward sign), computed once per kernel.
__device__ __forceinline__ void make_tw(int t, float2* tw0, float2* tw1){
  float sn, cs;
  __sincosf((TWOPI_F/512.0f)*(float)t, &sn, &cs);
  float2 w0 = make_float2(cs, -sn);
  tw0[0] = make_float2(1.0f, 0.0f);
  #pragma unroll
  for(int k=1;k<8;k++) tw0[k] = cmul(tw0[k-1], w0);
  int p = t>>3;
  __sincosf((TWOPI_F/64.0f)*(float)p, &sn, &cs);
  float2 w1 = make_float2(cs, -sn);
  tw1[0] = make_float2(1.0f, 0.0f);
  #pragma unroll
  for(int k=1;k<8;k++) tw1[k] = cmul(tw1[k-1], w1);
}

// 512-pt FFT, two-buffer ping-pong (row kernels). Input a[r]=elem(t+64r); o[k]=X[t+64k]*scale.
template<int S, int STRIDE>
__device__ __forceinline__ void fft512(float2* a, float2* o, float2* B0, float2* B1, int t,
                                       float scale, const float2* tw0, const float2* tw1){
  const int km[8] = {0,4,2,6,1,5,3,7};
  float2 d[8];
  dft8<S>(a, d);                                    // stage 0: n=512, s=1, p=t
  #pragma unroll
  for(int k=0;k<8;k++)
    B0[SWZ(8*t+k)*STRIDE] = (k==0) ? d[km[0]] : cmul_tw<S>(d[km[k]], tw0[k]);
  __syncthreads();
  #pragma unroll
  for(int r=0;r<8;r++) a[r] = B0[SWZ(t+64*r)*STRIDE];
  dft8<S>(a, d);                                    // stage 1: n=64, s=8
  {
    int p = t>>3, q = t&7;
    #pragma unroll
    for(int k=0;k<8;k++)
      B1[SWZ(q + 64*p + 8*k)*STRIDE] = (k==0) ? d[km[0]] : cmul_tw<S>(d[km[k]], tw1[k]);
  }
  __syncthreads();
  #pragma unroll
  for(int r=0;r<8;r++) a[r] = B1[SWZ(t+64*r)*STRIDE];
  dft8<S>(a, d);                                    // stage 2: n=8, s=64, no twiddle
  #pragma unroll
  for(int k=0;k<8;k++) o[k] = make_float2(d[km[k]].x*scale, d[km[k]].y*scale);
}

// 512-pt FFT, single shared buffer, stride 16 (col kernel). Caller must sync
// before the next write into B after this returns (last op is a read).
template<int S>
__device__ __forceinline__ void fft512_1b(float2* a, float2* o, float2* B, int t,
                                          float scale, const float2* tw0, const float2* tw1){
  const int km[8] = {0,4,2,6,1,5,3,7};
  float2 d[8];
  dft8<S>(a, d);                                    // stage 0
  #pragma unroll
  for(int k=0;k<8;k++)
    B[(8*t+k)*16] = (k==0) ? d[km[0]] : cmul_tw<S>(d[km[k]], tw0[k]);
  __syncthreads();
  #pragma unroll
  for(int r=0;r<8;r++) a[r] = B[(t+64*r)*16];
  __syncthreads();
  dft8<S>(a, d);                                    // stage 1
  {
    int p = t>>3, q = t&7;
    #pragma unroll
    for(int k=0;k<8;k++)
      B[(q + 64*p + 8*k)*16] = (k==0) ? d[km[0]] : cmul_tw<S>(d[km[k]], tw1[k]);
  }
  __syncthreads();
  #pragma unroll
  for(int r=0;r<8;r++) a[r] = B[(t+64*r)*16];
  dft8<S>(a, d);                                    // stage 2, regs only
  #pragma unroll
  for(int k=0;k<8;k++) o[k] = make_float2(d[km[k]].x*scale, d[km[k]].y*scale);
}

// --- Field accessors: interleaved (mode A) vs split planes (fallback) --------

struct AccI {
  float2* p;
  __device__ __forceinline__ float2 ld(int i) const { return p[i]; }
  __device__ __forceinline__ void   st(int i, float2 v) const { p[i] = v; }
};
struct AccS {
  float* re; float* im;
  __device__ __forceinline__ float2 ld(int i) const { return make_float2(re[i], im[i]); }
  __device__ __forceinline__ void   st(int i, float2 v) const { re[i]=v.x; im[i]=v.y; }
};

// --- H transfer-function tables: H1(z=0.03) and H12 = H(0.03)*H(0.05) --------

__device__ __forceinline__ float2 phase_of(float kz, float zf){
  float tt = __fmul_rn(kz, zf);
  double dt = (double)tt;                          // accurate mod-2pi reduction
  double q  = rint(dt * 0.15915494309189535);
  double rr = fma(-q, 6.283185307179586, dt);
  float sn, cs; __sincosf((float)rr, &sn, &cs);
  return make_float2(cs, sn);
}

__global__ __launch_bounds__(256) void k_htab(const float* __restrict__ lams,
                                              float2* __restrict__ H1, float2* __restrict__ H12){
  int e = blockIdx.x*256 + threadIdx.x;            // e < 3*512*512
  int c = e >> 18, fy = (e>>9)&511, col = e&511;
  const float lam = lams[c];
  const float il  = 1.0f / lam;
  const float il2 = __fmul_rn(il, il);
  const float DEN = (float)(512.0 * 8e-6);
  int   sx  = (col < 256) ? col : col - 512;
  int   sy  = (fy  < 256) ? fy  : fy  - 512;
  float fxv = (float)sx / DEN, fyv = (float)sy / DEN;
  float arg = __fsub_rn(il2, __fadd_rn(__fmul_rn(fxv,fxv), __fmul_rn(fyv,fyv)));
  float2 h1 = make_float2(0.0f,0.0f), h12 = h1;
  if(arg > 0.0f){
    float s  = (float)sqrt((double)arg);           // correctly-rounded f32 sqrt
    float kz = __fmul_rn(6.2831854820251465f, s);
    h1  = phase_of(kz, 0.03f);
    h12 = cmul(h1, phase_of(kz, 0.05f));
  }
  H1[e] = h1; H12[e] = h12;
}

// --- Row pass kernels: one wave per row, 4 rows per block ---------------------

template<class Acc>
__global__ __launch_bounds__(256) void k_row_first(
    const float* __restrict__ x, Acc f,
    const float* __restrict__ phases, const float* __restrict__ coeffs)
{
  __shared__ float2 lds[4][2][512];
  const int w = threadIdx.x >> 6, t = threadIdx.x & 63;
  const int img = blockIdx.x, c = img % 3;
  const int row = (blockIdx.y<<2) + w;
  const int base = (img*512 + row)*512;
  const float* ph = phases + row*512;              // layer 0
  const float coeff = coeffs[c];
  float2 tw0[8], tw1[8]; make_tw(t, tw0, tw1);
  float2 a[8], o[8];
  #pragma unroll
  for(int r=0;r<8;r++){
    int i = t + (r<<6);
    float xv = x[base+i];
    float th = __fmul_rn(ph[i], coeff);
    float sn, cs; __sincosf(th, &sn, &cs);
    a[r] = make_float2(xv*cs, xv*sn);
  }
  fft512<-1,1>(a, o, lds[w][0], lds[w][1], t, 1.0f, tw0, tw1);
  #pragma unroll
  for(int k=0;k<8;k++){ int i=t+(k<<6); f.st(base+i, o[k]); }
}

template<class Acc>
__global__ __launch_bounds__(256) void k_row_mid(
    Acc f, const float* __restrict__ phases, const float* __restrict__ coeffs, int layer)
{
  __shared__ float2 lds[4][2][512];
  const int w = threadIdx.x >> 6, t = threadIdx.x & 63;
  const int img = blockIdx.x, c = img % 3;
  const int row = (blockIdx.y<<2) + w;
  const int base = (img*512 + row)*512;
  const float* ph = phases + (layer*512 + row)*512;
  const float coeff = coeffs[layer*3 + c];
  float2 tw0[8], tw1[8]; make_tw(t, tw0, tw1);
  float2 a[8], o[8];
  #pragma unroll
  for(int r=0;r<8;r++){ int i=t+(r<<6); a[r]=f.ld(base+i); }
  fft512<+1,1>(a, o, lds[w][0], lds[w][1], t, 1.0f/512.0f, tw0, tw1);   // row IFFT
  #pragma unroll
  for(int k=0;k<8;k++){
    int i = t + (k<<6);
    float th = __fmul_rn(ph[i], coeff);
    float sn, cs; __sincosf(th, &sn, &cs);
    a[k] = cmul(o[k], make_float2(cs, sn));
  }
  fft512<-1,1>(a, o, lds[w][0], lds[w][1], t, 1.0f, tw0, tw1);          // row FFT
  #pragma unroll
  for(int k=0;k<8;k++){ int i=t+(k<<6); f.st(base+i, o[k]); }
}

template<class Acc>
__global__ __launch_bounds__(256) void k_row_last(
    Acc f, float* __restrict__ out)
{
  __shared__ float2 lds[4][2][512];
  const int w = threadIdx.x >> 6, t = threadIdx.x & 63;
  const int img = blockIdx.x;
  const int row = (blockIdx.y<<2) + w;
  const int base = (img*512 + row)*512;
  float2 tw0[8], tw1[8]; make_tw(t, tw0, tw1);
  float2 a[8], o[8];
  #pragma unroll
  for(int r=0;r<8;r++){ int i=t+(r<<6); a[r]=f.ld(base+i); }
  fft512<+1,1>(a, o, lds[w][0], lds[w][1], t, 1.0f/512.0f, tw0, tw1);   // row IFFT
  #pragma unroll
  for(int k=0;k<8;k++){ int i=t+(k<<6); out[base+i] = o[k].x*o[k].x + o[k].y*o[k].y; }
}

// --- Column pass: colFFT -> xH -> colIFFT; 16 cols / 1024-thread block --------
// Interleaved layout: 128B contiguous global segments. Single 64KB LDS buffer.

template<class Acc, bool TAB>
__global__ __launch_bounds__(1024, 4) void k_col16(
    Acc f, const float2* __restrict__ Htab, const float* __restrict__ lams, float z1, float z2)
{
  __shared__ float2 lds[512][16];       // 64 KiB; bank spread uniform at stride 16
  const int cx = threadIdx.x & 15, t = threadIdx.x >> 4;
  const int img = blockIdx.x, c = img % 3;
  const int col = (blockIdx.y<<4) + cx;
  const int ibase = (img<<18) + col;
  float2 tw0[8], tw1[8]; make_tw(t, tw0, tw1);
  float2 a[8], o[8];
  #pragma unroll
  for(int r=0;r<8;r++){ int gi = ibase + ((t+(r<<6))<<9); a[r]=f.ld(gi); }
  fft512_1b<-1>(a, o, &lds[0][cx], t, 1.0f, tw0, tw1);          // col FFT

  if(TAB){
    const float2* Hrow = Htab + (c<<18) + col;
    #pragma unroll
    for(int k=0;k<8;k++){
      int fy = t + (k<<6);
      float2 h = Hrow[fy<<9];
      a[k] = cmul(o[k], h);
    }
  } else {
    const float lam = lams[c];
    const float il  = 1.0f / lam;
    const float il2 = __fmul_rn(il, il);
    const float DEN = (float)(512.0 * 8e-6);
    int   sx  = (col < 256) ? col : col - 512;
    float fxv = (float)sx / DEN;
    float fx2 = __fmul_rn(fxv, fxv);
    #pragma unroll
    for(int k=0;k<8;k++){
      int fy = t + (k<<6);
      int sy = (fy < 256) ? fy : fy - 512;
      float fyv = (float)sy / DEN;
      float arg = __fsub_rn(il2, __fadd_rn(fx2, __fmul_rn(fyv,fyv)));
      float2 h = make_float2(0.0f, 0.0f);
      if(arg > 0.0f){
        float s  = (float)sqrt((double)arg);
        float kz = __fmul_rn(6.2831854820251465f, s);
        h = phase_of(kz, z1);
        if(z2 != 0.0f) h = cmul(h, phase_of(kz, z2));
      }
      a[k] = cmul(o[k], h);
    }
  }
  __syncthreads();                                               // LDS reuse fence
  fft512_1b<+1>(a, o, &lds[0][cx], t, 1.0f/512.0f, tw0, tw1);   // col IFFT
  #pragma unroll
  for(int k=0;k<8;k++){ int gi = ibase + ((t+(k<<6))<<9); f.st(gi, o[k]); }
}

// ---------------------------------------------------------------------------

extern "C" void kernel_launch(void* const* d_in, const int* in_sizes, int n_in,
                              void* d_out, int out_size, void* d_ws, size_t ws_size,
                              hipStream_t stream)
{
  const float* x      = (const float*)d_in[0];
  const float* phases = (const float*)d_in[1];
  const float* coeffs = (const float*)d_in[2];
  const float* lams   = (const float*)d_in[3];
  float* out = (float*)d_out;

  const size_t fldB = (size_t)NPIX*8;              // interleaved field: 100.7MB
  const size_t splB = (size_t)NPIX*4;              // split im plane:     50.3MB
  const size_t tabB = (size_t)3*512*512*8;         // one H table:         6.3MB

  dim3 gA(48,128), bA(256);
  dim3 gB(48,32),  bB(1024);

  if(ws_size >= fldB + 2*tabB){
    // --- mode A: interleaved field in ws ---
    AccI f { (float2*)d_ws };
    float2* H1  = (float2*)((char*)d_ws + fldB);
    float2* H12 = H1 + 3*512*512;
    k_htab<<<dim3(3*512*512/256), dim3(256), 0, stream>>>(lams, H1, H12);
    k_row_first<AccI><<<gA, bA, 0, stream>>>(x, f, phases, coeffs);
    for(int l=1; l<=3; l++){
      k_col16<AccI,true><<<gB, bB, 0, stream>>>(f, H1, lams, 0.03f, 0.0f);
      k_row_mid<AccI><<<gA, bA, 0, stream>>>(f, phases, coeffs, l);
    }
    k_col16<AccI,true><<<gB, bB, 0, stream>>>(f, H12, lams, 0.03f, 0.0f);
    k_row_last<AccI><<<gA, bA, 0, stream>>>(f, out);
  } else if(ws_size >= splB + 2*tabB){
    // --- mode B: split planes + tables ---
    AccS f { out, (float*)d_ws };
    float2* H1  = (float2*)((char*)d_ws + splB);
    float2* H12 = H1 + 3*512*512;
    k_htab<<<dim3(3*512*512/256), dim3(256), 0, stream>>>(lams, H1, H12);
    k_row_first<AccS><<<gA, bA, 0, stream>>>(x, f, phases, coeffs);
    for(int l=1; l<=3; l++){
      k_col16<AccS,true><<<gB, bB, 0, stream>>>(f, H1, lams, 0.03f, 0.0f);
      k_row_mid<AccS><<<gA, bA, 0, stream>>>(f, phases, coeffs, l);
    }
    k_col16<AccS,true><<<gB, bB, 0, stream>>>(f, H12, lams, 0.03f, 0.0f);
    k_row_last<AccS><<<gA, bA, 0, stream>>>(f, out);
  } else {
    // --- mode C: split planes, inline H ---
    AccS f { out, (float*)d_ws };
    k_row_first<AccS><<<gA, bA, 0, stream>>>(x, f, phases, coeffs);
    for(int l=1; l<=3; l++){
      k_col16<AccS,false><<<gB, bB, 0, stream>>>(f, nullptr, lams, 0.03f, 0.0f);
      k_row_mid<AccS><<<gA, bA, 0, stream>>>(f, phases, coeffs, l);
    }
    k_col16<AccS,false><<<gB, bB, 0, stream>>>(f, nullptr, lams, 0.03f, 0.05f);
    k_row_last<AccS><<<gA, bA, 0, stream>>>(f, out);
  }
}

// Round 6
// 346.491 us; speedup vs baseline: 1.6548x; 1.0655x over previous
//
#include <hip/hip_runtime.h>
#include <math.h>

// ---------------------------------------------------------------------------
// Multi-layer diffractive optical model (4 layers, 48 images of 512x512 c64).
//   field = x*exp(i*phase*coeff); 4x [prop(H1); phase]; prop(H1*Hf); |field|^2
// FFT: 512-pt radix-8 Stockham, 3 stages, 64 lanes/transform, 8 elems/lane.
// Row pass fuses rowIFFT -> phase -> rowFFT; col pass fuses colFFT -> xH -> colIFFT.
// Col pass v3: 8 cols / 512-thread block, single padded LDS buffer [512][9]
//   (36KB -> 4 blocks/CU, occupancy ceiling 100% vs 36% for the 1024-thr/64KB
//   version), H prefetched to registers before the forward FFT.
// Row swizzle i^((i>>4)&7): reaches the b64 4-lane/bank floor (old (i>>3)
//   variant left 8-way conflicts on stage writes).
// Field: interleaved float2 in d_ws (mode A); split-plane fallbacks B/C.
// ---------------------------------------------------------------------------

#define TWOPI_F 6.2831854820251465f
#define RSQ2    0.70710678f
#define NPIX    (48*512*512)

__device__ __forceinline__ float2 cadd(float2 a, float2 b){ return make_float2(a.x+b.x, a.y+b.y); }
__device__ __forceinline__ float2 csub(float2 a, float2 b){ return make_float2(a.x-b.x, a.y-b.y); }
__device__ __forceinline__ float2 cmul(float2 a, float2 b){ return make_float2(a.x*b.x - a.y*b.y, a.x*b.y + a.y*b.x); }

template<int S> __device__ __forceinline__ float2 mul_i(float2 a){   // * (S*i)
  return (S>0) ? make_float2(-a.y, a.x) : make_float2(a.y, -a.x);
}
template<int S> __device__ __forceinline__ float2 mul_w1(float2 a){  // * (1 + S*i)/sqrt2
  return (S>0) ? make_float2(RSQ2*(a.x-a.y), RSQ2*(a.x+a.y))
               : make_float2(RSQ2*(a.x+a.y), RSQ2*(a.y-a.x));
}
template<int S> __device__ __forceinline__ float2 mul_w3(float2 a){  // * (-1 + S*i)/sqrt2
  return (S>0) ? make_float2(RSQ2*(-a.x-a.y), RSQ2*(a.x-a.y))
               : make_float2(RSQ2*(a.y-a.x), RSQ2*(-a.x-a.y));
}
// tw stored with FORWARD sign (exp(-i theta)); S=+1 uses conjugate.
template<int S> __device__ __forceinline__ float2 cmul_tw(float2 v, float2 w){
  float wy = (S>0) ? -w.y : w.y;
  return make_float2(v.x*w.x - v.y*wy, v.x*wy + v.y*w.x);
}

// 8-point DIF DFT; outputs bit-reversed: A_k = d[km[k]], km = {0,4,2,6,1,5,3,7}
template<int S>
__device__ __forceinline__ void dft8(const float2* a, float2* d){
  float2 b0=cadd(a[0],a[4]), b1=cadd(a[1],a[5]), b2=cadd(a[2],a[6]), b3=cadd(a[3],a[7]);
  float2 b4=csub(a[0],a[4]);
  float2 b5=mul_w1<S>(csub(a[1],a[5]));
  float2 b6=mul_i<S> (csub(a[2],a[6]));
  float2 b7=mul_w3<S>(csub(a[3],a[7]));
  float2 c0=cadd(b0,b2), c2=csub(b0,b2);
  float2 c1=cadd(b1,b3), c3=mul_i<S>(csub(b1,b3));
  float2 c4=cadd(b4,b6), c6=csub(b4,b6);
  float2 c5=cadd(b5,b7), c7=mul_i<S>(csub(b5,b7));
  d[0]=cadd(c0,c1); d[1]=csub(c0,c1);
  d[2]=cadd(c2,c3); d[3]=csub(c2,c3);
  d[4]=cadd(c4,c5); d[5]=csub(c4,c5);
  d[6]=cadd(c6,c7); d[7]=csub(c6,c7);
}

// LDS swizzle for stride-1 row buffers. Involution; spreads any fixed-k
// ds_write_b64 across 16 bank-pairs (the 4-lane/bank b64 floor).
__device__ __forceinline__ int SWZR(int i){ return i ^ ((i>>4)&7); }

// Per-thread twiddles (forward sign), computed once per kernel.
__device__ __forceinline__ void make_tw(int t, float2* tw0, float2* tw1){
  float sn, cs;
  __sincosf((TWOPI_F/512.0f)*(float)t, &sn, &cs);
  float2 w0 = make_float2(cs, -sn);
  tw0[0] = make_float2(1.0f, 0.0f);
  #pragma unroll
  for(int k=1;k<8;k++) tw0[k] = cmul(tw0[k-1], w0);
  int p = t>>3;
  __sincosf((TWOPI_F/64.0f)*(float)p, &sn, &cs);
  float2 w1 = make_float2(cs, -sn);
  tw1[0] = make_float2(1.0f, 0.0f);
  #pragma unroll
  for(int k=1;k<8;k++) tw1[k] = cmul(tw1[k-1], w1);
}

// 512-pt FFT, two-buffer ping-pong, stride-1 + SWZR (row kernels).
// Input a[r]=elem(t+64r); output o[k]=X[t+64k]*scale.
template<int S>
__device__ __forceinline__ void fft512(float2* a, float2* o, float2* B0, float2* B1, int t,
                                       float scale, const float2* tw0, const float2* tw1){
  const int km[8] = {0,4,2,6,1,5,3,7};
  float2 d[8];
  dft8<S>(a, d);                                    // stage 0: n=512, s=1, p=t
  #pragma unroll
  for(int k=0;k<8;k++)
    B0[SWZR(8*t+k)] = (k==0) ? d[km[0]] : cmul_tw<S>(d[km[k]], tw0[k]);
  __syncthreads();
  #pragma unroll
  for(int r=0;r<8;r++) a[r] = B0[SWZR(t+64*r)];
  dft8<S>(a, d);                                    // stage 1: n=64, s=8
  {
    int p = t>>3, q = t&7;
    #pragma unroll
    for(int k=0;k<8;k++)
      B1[SWZR(q + 64*p + 8*k)] = (k==0) ? d[km[0]] : cmul_tw<S>(d[km[k]], tw1[k]);
  }
  __syncthreads();
  #pragma unroll
  for(int r=0;r<8;r++) a[r] = B1[SWZR(t+64*r)];
  dft8<S>(a, d);                                    // stage 2: n=8, s=64, no twiddle
  #pragma unroll
  for(int k=0;k<8;k++) o[k] = make_float2(d[km[k]].x*scale, d[km[k]].y*scale);
}

// 512-pt FFT, single shared buffer, element stride LD (col kernel; LD=9 pads
// away bank conflicts). Caller must barrier before reusing B for writes.
template<int S, int LD>
__device__ __forceinline__ void fft512_1b(float2* a, float2* o, float2* B, int t,
                                          float scale, const float2* tw0, const float2* tw1){
  const int km[8] = {0,4,2,6,1,5,3,7};
  float2 d[8];
  dft8<S>(a, d);                                    // stage 0
  #pragma unroll
  for(int k=0;k<8;k++)
    B[(8*t+k)*LD] = (k==0) ? d[km[0]] : cmul_tw<S>(d[km[k]], tw0[k]);
  __syncthreads();
  #pragma unroll
  for(int r=0;r<8;r++) a[r] = B[(t+64*r)*LD];
  __syncthreads();
  dft8<S>(a, d);                                    // stage 1
  {
    int p = t>>3, q = t&7;
    #pragma unroll
    for(int k=0;k<8;k++)
      B[(q + 64*p + 8*k)*LD] = (k==0) ? d[km[0]] : cmul_tw<S>(d[km[k]], tw1[k]);
  }
  __syncthreads();
  #pragma unroll
  for(int r=0;r<8;r++) a[r] = B[(t+64*r)*LD];
  dft8<S>(a, d);                                    // stage 2, regs only
  #pragma unroll
  for(int k=0;k<8;k++) o[k] = make_float2(d[km[k]].x*scale, d[km[k]].y*scale);
}

// --- Field accessors: interleaved (mode A) vs split planes (fallback) --------

struct AccI {
  float2* p;
  __device__ __forceinline__ float2 ld(int i) const { return p[i]; }
  __device__ __forceinline__ void   st(int i, float2 v) const { p[i] = v; }
};
struct AccS {
  float* re; float* im;
  __device__ __forceinline__ float2 ld(int i) const { return make_float2(re[i], im[i]); }
  __device__ __forceinline__ void   st(int i, float2 v) const { re[i]=v.x; im[i]=v.y; }
};

// --- H transfer-function tables: H1(z=0.03) and H12 = H(0.03)*H(0.05) --------

__device__ __forceinline__ float2 phase_of(float kz, float zf){
  float tt = __fmul_rn(kz, zf);
  double dt = (double)tt;                          // accurate mod-2pi reduction
  double q  = rint(dt * 0.15915494309189535);
  double rr = fma(-q, 6.283185307179586, dt);
  float sn, cs; __sincosf((float)rr, &sn, &cs);
  return make_float2(cs, sn);
}

__global__ __launch_bounds__(256) void k_htab(const float* __restrict__ lams,
                                              float2* __restrict__ H1, float2* __restrict__ H12){
  int e = blockIdx.x*256 + threadIdx.x;            // e < 3*512*512
  int c = e >> 18, fy = (e>>9)&511, col = e&511;
  const float lam = lams[c];
  const float il  = 1.0f / lam;
  const float il2 = __fmul_rn(il, il);
  const float DEN = (float)(512.0 * 8e-6);
  int   sx  = (col < 256) ? col : col - 512;
  int   sy  = (fy  < 256) ? fy  : fy  - 512;
  float fxv = (float)sx / DEN, fyv = (float)sy / DEN;
  float arg = __fsub_rn(il2, __fadd_rn(__fmul_rn(fxv,fxv), __fmul_rn(fyv,fyv)));
  float2 h1 = make_float2(0.0f,0.0f), h12 = h1;
  if(arg > 0.0f){
    float s  = (float)sqrt((double)arg);           // correctly-rounded f32 sqrt
    float kz = __fmul_rn(6.2831854820251465f, s);
    h1  = phase_of(kz, 0.03f);
    h12 = cmul(h1, phase_of(kz, 0.05f));
  }
  H1[e] = h1; H12[e] = h12;
}

// --- Row pass kernels: one wave per row, 4 rows per block ---------------------

template<class Acc>
__global__ __launch_bounds__(256) void k_row_first(
    const float* __restrict__ x, Acc f,
    const float* __restrict__ phases, const float* __restrict__ coeffs)
{
  __shared__ float2 lds[4][2][512];
  const int w = threadIdx.x >> 6, t = threadIdx.x & 63;
  const int img = blockIdx.x, c = img % 3;
  const int row = (blockIdx.y<<2) + w;
  const int base = (img*512 + row)*512;
  const float* ph = phases + row*512;              // layer 0
  const float coeff = coeffs[c];
  float2 tw0[8], tw1[8]; make_tw(t, tw0, tw1);
  float2 a[8], o[8];
  #pragma unroll
  for(int r=0;r<8;r++){
    int i = t + (r<<6);
    float xv = x[base+i];
    float th = __fmul_rn(ph[i], coeff);
    float sn, cs; __sincosf(th, &sn, &cs);
    a[r] = make_float2(xv*cs, xv*sn);
  }
  fft512<-1>(a, o, lds[w][0], lds[w][1], t, 1.0f, tw0, tw1);
  #pragma unroll
  for(int k=0;k<8;k++){ int i=t+(k<<6); f.st(base+i, o[k]); }
}

template<class Acc>
__global__ __launch_bounds__(256) void k_row_mid(
    Acc f, const float* __restrict__ phases, const float* __restrict__ coeffs, int layer)
{
  __shared__ float2 lds[4][2][512];
  const int w = threadIdx.x >> 6, t = threadIdx.x & 63;
  const int img = blockIdx.x, c = img % 3;
  const int row = (blockIdx.y<<2) + w;
  const int base = (img*512 + row)*512;
  const float* ph = phases + (layer*512 + row)*512;
  const float coeff = coeffs[layer*3 + c];
  float2 tw0[8], tw1[8]; make_tw(t, tw0, tw1);
  float2 a[8], o[8];
  float phr[8];
  #pragma unroll
  for(int r=0;r<8;r++){ int i=t+(r<<6); a[r]=f.ld(base+i); phr[r]=ph[i]; }
  fft512<+1>(a, o, lds[w][0], lds[w][1], t, 1.0f/512.0f, tw0, tw1);   // row IFFT
  #pragma unroll
  for(int k=0;k<8;k++){
    float th = __fmul_rn(phr[k], coeff);
    float sn, cs; __sincosf(th, &sn, &cs);
    a[k] = cmul(o[k], make_float2(cs, sn));
  }
  fft512<-1>(a, o, lds[w][0], lds[w][1], t, 1.0f, tw0, tw1);          // row FFT
  #pragma unroll
  for(int k=0;k<8;k++){ int i=t+(k<<6); f.st(base+i, o[k]); }
}

template<class Acc>
__global__ __launch_bounds__(256) void k_row_last(
    Acc f, float* __restrict__ out)
{
  __shared__ float2 lds[4][2][512];
  const int w = threadIdx.x >> 6, t = threadIdx.x & 63;
  const int img = blockIdx.x;
  const int row = (blockIdx.y<<2) + w;
  const int base = (img*512 + row)*512;
  float2 tw0[8], tw1[8]; make_tw(t, tw0, tw1);
  float2 a[8], o[8];
  #pragma unroll
  for(int r=0;r<8;r++){ int i=t+(r<<6); a[r]=f.ld(base+i); }
  fft512<+1>(a, o, lds[w][0], lds[w][1], t, 1.0f/512.0f, tw0, tw1);   // row IFFT
  #pragma unroll
  for(int k=0;k<8;k++){ int i=t+(k<<6); out[base+i] = o[k].x*o[k].x + o[k].y*o[k].y; }
}

// --- Column pass v3: colFFT -> xH -> colIFFT; 8 cols / 512-thread block -------
// Single padded 36KB LDS buffer -> 4 blocks/CU; H prefetched before the FFT.

template<class Acc, bool TAB>
__global__ __launch_bounds__(512, 4) void k_col8(
    Acc f, const float2* __restrict__ Htab, const float* __restrict__ lams, float z1, float z2)
{
  __shared__ float2 lds[512][9];        // 36 KiB; pad 9 -> b64 bank floor
  const int cx = threadIdx.x & 7, t = threadIdx.x >> 3;
  const int img = blockIdx.x, c = img % 3;
  const int col = (blockIdx.y<<3) + cx;
  const int ibase = (img<<18) + col;
  float2 tw0[8], tw1[8]; make_tw(t, tw0, tw1);
  float2 a[8], o[8], h[8];
  #pragma unroll
  for(int r=0;r<8;r++){ int gi = ibase + ((t+(r<<6))<<9); a[r]=f.ld(gi); }
  if(TAB){
    const float2* Hrow = Htab + (c<<18) + col;     // prefetch H (independent of FFT)
    #pragma unroll
    for(int k=0;k<8;k++) h[k] = Hrow[(t+(k<<6))<<9];
  } else {
    const float lam = lams[c];
    const float il  = 1.0f / lam;
    const float il2 = __fmul_rn(il, il);
    const float DEN = (float)(512.0 * 8e-6);
    int   sx  = (col < 256) ? col : col - 512;
    float fxv = (float)sx / DEN;
    float fx2 = __fmul_rn(fxv, fxv);
    #pragma unroll
    for(int k=0;k<8;k++){
      int fy = t + (k<<6);
      int sy = (fy < 256) ? fy : fy - 512;
      float fyv = (float)sy / DEN;
      float arg = __fsub_rn(il2, __fadd_rn(fx2, __fmul_rn(fyv,fyv)));
      h[k] = make_float2(0.0f, 0.0f);
      if(arg > 0.0f){
        float s  = (float)sqrt((double)arg);
        float kz = __fmul_rn(6.2831854820251465f, s);
        h[k] = phase_of(kz, z1);
        if(z2 != 0.0f) h[k] = cmul(h[k], phase_of(kz, z2));
      }
    }
  }
  fft512_1b<-1,9>(a, o, &lds[0][cx], t, 1.0f, tw0, tw1);          // col FFT
  #pragma unroll
  for(int k=0;k<8;k++) a[k] = cmul(o[k], h[k]);
  __syncthreads();                                                 // LDS reuse fence
  fft512_1b<+1,9>(a, o, &lds[0][cx], t, 1.0f/512.0f, tw0, tw1);   // col IFFT
  #pragma unroll
  for(int k=0;k<8;k++){ int gi = ibase + ((t+(k<<6))<<9); f.st(gi, o[k]); }
}

// ---------------------------------------------------------------------------

extern "C" void kernel_launch(void* const* d_in, const int* in_sizes, int n_in,
                              void* d_out, int out_size, void* d_ws, size_t ws_size,
                              hipStream_t stream)
{
  const float* x      = (const float*)d_in[0];
  const float* phases = (const float*)d_in[1];
  const float* coeffs = (const float*)d_in[2];
  const float* lams   = (const float*)d_in[3];
  float* out = (float*)d_out;

  const size_t fldB = (size_t)NPIX*8;              // interleaved field: 100.7MB
  const size_t splB = (size_t)NPIX*4;              // split im plane:     50.3MB
  const size_t tabB = (size_t)3*512*512*8;         // one H table:         6.3MB

  dim3 gA(48,128), bA(256);
  dim3 gB(48,64),  bB(512);

  if(ws_size >= fldB + 2*tabB){
    // --- mode A: interleaved field in ws ---
    AccI f { (float2*)d_ws };
    float2* H1  = (float2*)((char*)d_ws + fldB);
    float2* H12 = H1 + 3*512*512;
    k_htab<<<dim3(3*512*512/256), dim3(256), 0, stream>>>(lams, H1, H12);
    k_row_first<AccI><<<gA, bA, 0, stream>>>(x, f, phases, coeffs);
    for(int l=1; l<=3; l++){
      k_col8<AccI,true><<<gB, bB, 0, stream>>>(f, H1, lams, 0.03f, 0.0f);
      k_row_mid<AccI><<<gA, bA, 0, stream>>>(f, phases, coeffs, l);
    }
    k_col8<AccI,true><<<gB, bB, 0, stream>>>(f, H12, lams, 0.03f, 0.0f);
    k_row_last<AccI><<<gA, bA, 0, stream>>>(f, out);
  } else if(ws_size >= splB + 2*tabB){
    // --- mode B: split planes + tables ---
    AccS f { out, (float*)d_ws };
    float2* H1  = (float2*)((char*)d_ws + splB);
    float2* H12 = H1 + 3*512*512;
    k_htab<<<dim3(3*512*512/256), dim3(256), 0, stream>>>(lams, H1, H12);
    k_row_first<AccS><<<gA, bA, 0, stream>>>(x, f, phases, coeffs);
    for(int l=1; l<=3; l++){
      k_col8<AccS,true><<<gB, bB, 0, stream>>>(f, H1, lams, 0.03f, 0.0f);
      k_row_mid<AccS><<<gA, bA, 0, stream>>>(f, phases, coeffs, l);
    }
    k_col8<AccS,true><<<gB, bB, 0, stream>>>(f, H12, lams, 0.03f, 0.0f);
    k_row_last<AccS><<<gA, bA, 0, stream>>>(f, out);
  } else {
    // --- mode C: split planes, inline H ---
    AccS f { out, (float*)d_ws };
    k_row_first<AccS><<<gA, bA, 0, stream>>>(x, f, phases, coeffs);
    for(int l=1; l<=3; l++){
      k_col8<AccS,false><<<gB, bB, 0, stream>>>(f, nullptr, lams, 0.03f, 0.0f);
      k_row_mid<AccS><<<gA, bA, 0, stream>>>(f, phases, coeffs, l);
    }
    k_col8<AccS,false><<<gB, bB, 0, stream>>>(f, nullptr, lams, 0.03f, 0.05f);
    k_row_last<AccS><<<gA, bA, 0, stream>>>(f, out);
  }
}